// Round 8
// baseline (197.923 us; speedup 1.0000x reference)
//
#include <hip/hip_runtime.h>

typedef __bf16 bf16x8 __attribute__((ext_vector_type(8)));
typedef float f32x4 __attribute__((ext_vector_type(4)));
typedef float f32x16 __attribute__((ext_vector_type(16)));

#define MFMA16(a, b, c) __builtin_amdgcn_mfma_f32_16x16x32_bf16(a, b, c, 0, 0, 0)
#define MFMA32(a, b, c) __builtin_amdgcn_mfma_f32_32x32x16_bf16(a, b, c, 0, 0, 0)
#define GLDS16(g, l)                                                              \
  __builtin_amdgcn_global_load_lds((const __attribute__((address_space(1))) void*)(g), \
                                   (__attribute__((address_space(3))) void*)(l), 16, 0, 0)

static __device__ __forceinline__ unsigned cvt_pk_bf16(float lo, float hi) {
  unsigned r;
  asm("v_cvt_pk_bf16_f32 %0, %1, %2" : "=v"(r) : "v"(lo), "v"(hi));
  return r;
}
// v_permlane32_swap_b32: a'[l<32]=a[l], a'[l>=32]=b[l-32], b'[l<32]=a[l+32], b'[l>=32]=b[l]
static __device__ __forceinline__ void permswap(unsigned& a, unsigned& b) {
  asm("v_permlane32_swap_b32 %0, %1" : "+v"(a), "+v"(b));
}

// ---------------- prep: cvt x->bf16 (blocks 0-4095) + transpose both weights ----------------
__global__ __launch_bounds__(256) void prep_kernel(const float* __restrict__ x,
                                                   __bf16* __restrict__ xb,
                                                   const float* __restrict__ Wq,
                                                   __bf16* __restrict__ WqT,
                                                   const float* __restrict__ Wo,
                                                   __bf16* __restrict__ WoT) {
  __shared__ float tile[32][33];
  int bid = blockIdx.x;
  int tid = threadIdx.x;
  if (bid < 4096) {  // cvt: 1048576 float4 chunks
    int i = bid * 256 + tid;
    float4 v = ((const float4*)x)[i];
    union { __bf16 b[4]; uint2 u; } t;
    t.b[0] = (__bf16)v.x; t.b[1] = (__bf16)v.y;
    t.b[2] = (__bf16)v.z; t.b[3] = (__bf16)v.w;
    ((uint2*)xb)[i] = t.u;
    return;
  }
  // transpose-convert weights (block-uniform path; barrier only inside this branch)
  const int Kd = 1024;
  int b2 = bid - 4096;
  int bx = b2 & 127;
  int k0 = (b2 >> 7) * 32;
  const float* W; __bf16* WT; int Nd, n0;
  if (bx < 96) { W = Wq; WT = WqT; Nd = 3072; n0 = bx * 32; }
  else         { W = Wo; WT = WoT; Nd = 1024; n0 = (bx - 96) * 32; }
  int kk = tid >> 3, nn = (tid & 7) * 4;
  float4 v = *(const float4*)&W[(size_t)(k0 + kk) * Nd + n0 + nn];
  tile[kk][nn] = v.x; tile[kk][nn + 1] = v.y;
  tile[kk][nn + 2] = v.z; tile[kk][nn + 3] = v.w;
  __syncthreads();
  int n2 = tid >> 3, k2 = (tid & 7) * 4;
  union { __bf16 b[4]; uint2 u; } t;
  t.b[0] = (__bf16)tile[k2][n2];
  t.b[1] = (__bf16)tile[k2 + 1][n2];
  t.b[2] = (__bf16)tile[k2 + 2][n2];
  t.b[3] = (__bf16)tile[k2 + 3][n2];
  *(uint2*)&WT[(size_t)(n0 + n2) * Kd + k0 + k2] = t.u;
}

// ---------------- GEMM: C[M,N] = A[M,1024] @ BT[N,1024]^T + bias ----------------
// (round-4 verified core). V-fusion: when VtOut != nullptr and n0 >= 2048 (the V
// slice of qkv), also store each biased bf16 value transposed into Vt[b][h][d][t].
// Scatter is L2-absorbed: for fixed d this block writes the full 128-t range, so
// every 128B line is fully dirtied before eviction (no write amplification).
template <bool OUT_F32, int NT>
__global__ __launch_bounds__(256) void gemm_kernel(const __bf16* __restrict__ A,
                                                   const __bf16* __restrict__ BT,
                                                   const float* __restrict__ bias,
                                                   void* __restrict__ Cout, int N,
                                                   int qn, float qs,
                                                   __bf16* __restrict__ VtOut) {
  const int K = 1024;
  const int NJ = NT / 32;
  __shared__ __align__(16) __bf16 As[128 * 32];
  __shared__ __align__(16) __bf16 Bs[NT * 32];
  int tid = threadIdx.x;
  int wave = tid >> 6, lane = tid & 63;
  int quad = lane >> 4, l16 = lane & 15;
  int m0 = blockIdx.x * 128, n0 = blockIdx.y * NT;
  int wm = (wave >> 1) * 64, wn = (wave & 1) * (NT / 2);

  int srow = tid >> 2, scol = (tid & 3) * 8;
  const __bf16* aptr = A + (size_t)(m0 + srow) * K + scol;
  const __bf16* bptr = BT + (size_t)(n0 + srow) * K + scol;
  __bf16* asl = &As[(size_t)wave * 512];
  __bf16* bsl = &Bs[(size_t)wave * 512];

  f32x4 acc[4][NJ] = {};
  for (int k0 = 0; k0 < K; k0 += 32) {
    GLDS16(aptr + k0, asl);
    GLDS16(aptr + (size_t)64 * K + k0, asl + 2048);
    GLDS16(bptr + k0, bsl);
    if (NT == 128) GLDS16(bptr + (size_t)64 * K + k0, bsl + 2048);
    __syncthreads();
    bf16x8 af[4], bf[NJ];
    for (int i = 0; i < 4; i++)
      af[i] = *(bf16x8*)&As[(wm + i * 16 + l16) * 32 + quad * 8];
    for (int j = 0; j < NJ; j++)
      bf[j] = *(bf16x8*)&Bs[(wn + j * 16 + l16) * 32 + quad * 8];
    for (int i = 0; i < 4; i++)
      for (int j = 0; j < NJ; j++)
        acc[i][j] = MFMA16(af[i], bf[j], acc[i][j]);
    __syncthreads();
  }
  bool doV = (VtOut != nullptr) && (n0 >= 2048);
  for (int j = 0; j < NJ; j++) {
    int col = n0 + wn + j * 16 + l16;
    float bv = bias[col];
    float sc = (col < qn) ? qs : 1.0f;
    int cc = col - 2048;
    __bf16* vt = doV ? VtOut + ((size_t)(cc >> 6) * 64 + (cc & 63)) * 2048 : nullptr;
    for (int i = 0; i < 4; i++) {
      int rowb = m0 + wm + i * 16 + quad * 4;
      for (int r = 0; r < 4; r++) {
        float v = (acc[i][j][r] + bv) * sc;
        if (OUT_F32)
          ((float*)Cout)[(size_t)(rowb + r) * N + col] = v;
        else
          ((__bf16*)Cout)[(size_t)(rowb + r) * N + col] = (__bf16)v;
        if (doV) {
          int t_ = rowb + r;
          // Vt[b][h][dd][t]: b = t_>>11 adds b*16*64*2048
          vt[((size_t)(t_ >> 11) * 16 * 64) * 2048 + (t_ & 2047)] = (__bf16)v;
        }
      }
    }
  }
}

// ---------------- flash attention: T15 pipeline + 2nd-order XOR swizzle ----------------
// Swapped QK^T (S^T = mfma(K,Q)); in-register softmax via cvt_pk+permlane32_swap.
// Pipeline: iter t runs QK(t+1) [MFMA] then softmax(t) [VALU] then PV(t) [MFMA].
// LDS: single arena KV[4] = {K0,V0,K1,V1}, compile-time buffer selection.
// Swizzle slot = logical ^ (row&7) ^ ((row>>3)&7), applied on both sides.
struct AttnState {
  const char* lbase;
  char* wdst;
  int dK, dV;     // element deltas: +32 rows incl. swizzle adjustment
  int lb[2][4];
};

template <int KRD, int VRD, int KST, int VST, bool DO_KST>
__device__ __forceinline__ void attn_iter(const AttnState& st, const __bf16* kg,
                                          const __bf16* vg, const bf16x8 (&qf)[4],
                                          const f32x16* sIN, f32x16* sOUT, f32x16& o0,
                                          f32x16& o1, float& rs) {
  __syncthreads();  // drains own vmcnt: K(t+1),V(t) landed (all waves) before reads
  if constexpr (DO_KST) {
    GLDS16(kg, st.wdst + KST);
    GLDS16(kg + st.dK, st.wdst + KST + 4096);
  }
  GLDS16(vg, st.wdst + VST);
  GLDS16(vg + st.dV, st.wdst + VST + 4096);

  bf16x8 kf[2][4], vf[2][4];
#pragma unroll
  for (int rb = 0; rb < 2; rb++)
#pragma unroll
    for (int ds = 0; ds < 4; ds++)
      kf[rb][ds] = *(const bf16x8*)(st.lbase + st.lb[rb][ds] + KRD);
#pragma unroll
  for (int db = 0; db < 2; db++)
#pragma unroll
    for (int k2 = 0; k2 < 4; k2++)
      vf[db][k2] = *(const bf16x8*)(st.lbase + st.lb[db][k2] + VRD);

  f32x16 s0 = {}, s1 = {};
#pragma unroll
  for (int ds = 0; ds < 4; ds++) {
    s0 = MFMA32(kf[0][ds], qf[ds], s0);
    s1 = MFMA32(kf[1][ds], qf[ds], s1);
  }
  sOUT[0] = s0;
  sOUT[1] = s1;

  bf16x8 ap[4];
#pragma unroll
  for (int kb = 0; kb < 2; kb++) {
    float pv[16];
#pragma unroll
    for (int r = 0; r < 16; r++) {
      pv[r] = __builtin_amdgcn_exp2f(sIN[kb][r]);
      rs += pv[r];
    }
#pragma unroll
    for (int hf = 0; hf < 2; hf++) {
      unsigned w0 = cvt_pk_bf16(pv[hf * 8 + 0], pv[hf * 8 + 1]);
      unsigned w1 = cvt_pk_bf16(pv[hf * 8 + 2], pv[hf * 8 + 3]);
      unsigned w2 = cvt_pk_bf16(pv[hf * 8 + 4], pv[hf * 8 + 5]);
      unsigned w3 = cvt_pk_bf16(pv[hf * 8 + 6], pv[hf * 8 + 7]);
      permswap(w0, w2);
      permswap(w1, w3);
      union { unsigned u[4]; bf16x8 v; } pk;
      pk.u[0] = w0; pk.u[1] = w1; pk.u[2] = w2; pk.u[3] = w3;
      ap[kb * 2 + hf] = pk.v;
    }
  }

#pragma unroll
  for (int k2 = 0; k2 < 4; k2++) {
    o0 = MFMA32(ap[k2], vf[0][k2], o0);
    o1 = MFMA32(ap[k2], vf[1][k2], o1);
  }
}

__global__ __launch_bounds__(256, 2) void attn_kernel(const __bf16* __restrict__ qkv,
                                                      const __bf16* __restrict__ Vt,
                                                      __bf16* __restrict__ O) {
  const int T = 2048, C3 = 3072;
  int p = blockIdx.x * 4 + (blockIdx.y >> 4);
  int b = p >> 4, h = p & 15;
  int q0 = (blockIdx.y & 15) * 128;

  int tid = threadIdx.x, wave = tid >> 6, lane = tid & 63;
  int l32 = lane & 31, hi = lane >> 5;

  __shared__ __align__(16) __bf16 KV[4][64 * 64];

  const __bf16* qp = qkv + (size_t)(b * T + q0 + wave * 32 + l32) * C3 + h * 64;
  bf16x8 qf[4];
#pragma unroll
  for (int ds = 0; ds < 4; ds++)
    qf[ds] = *(const bf16x8*)(qp + ds * 16 + hi * 8);

  const __bf16* kbase = qkv + (size_t)(b * T) * C3 + 1024 + h * 64;
  const __bf16* vbase = Vt + (size_t)(b * 16 + h) * 64 * T;

  int srow = wave * 8 + (lane >> 3);
  int sx1 = ((lane & 7) ^ (lane >> 3) ^ wave) * 8;
  int sx2 = sx1 ^ 32;  // (^4 col-blocks) * 8 elem
  const __bf16* ksrc = kbase + (size_t)srow * C3 + sx1;
  const __bf16* vsrc = vbase + (size_t)srow * T + sx1;

  AttnState st;
  st.lbase = (const char*)&KV[0][0];
  st.wdst = (char*)&KV[0][0] + wave * 1024;
  st.dK = 32 * C3 + (sx2 - sx1);
  st.dV = 32 * T + (sx2 - sx1);
#pragma unroll
  for (int rb = 0; rb < 2; rb++)
#pragma unroll
    for (int c4 = 0; c4 < 4; c4++)
      st.lb[rb][c4] =
          ((rb * 32 + l32) * 64 +
           (((c4 * 2 + hi) ^ (l32 & 7) ^ (l32 >> 3) ^ (rb * 4)) * 8)) * 2;

  f32x16 o0 = {}, o1 = {};
  f32x16 sA[2], sB[2];
  float rs = 0.0f;

  GLDS16(ksrc, st.wdst + 0);
  GLDS16(ksrc + st.dK, st.wdst + 4096);
  GLDS16(vsrc, st.wdst + 8192);
  GLDS16(vsrc + st.dV, st.wdst + 8192 + 4096);
  GLDS16(ksrc + (size_t)64 * C3, st.wdst + 16384);
  GLDS16(ksrc + (size_t)64 * C3 + st.dK, st.wdst + 16384 + 4096);
  __syncthreads();

  {
    bf16x8 kf[2][4];
#pragma unroll
    for (int rb = 0; rb < 2; rb++)
#pragma unroll
      for (int ds = 0; ds < 4; ds++)
        kf[rb][ds] = *(const bf16x8*)(st.lbase + st.lb[rb][ds] + 0);
    f32x16 s0 = {}, s1 = {};
#pragma unroll
    for (int ds = 0; ds < 4; ds++) {
      s0 = MFMA32(kf[0][ds], qf[ds], s0);
      s1 = MFMA32(kf[1][ds], qf[ds], s1);
    }
    sA[0] = s0;
    sA[1] = s1;
  }

  const size_t kstep = (size_t)64 * C3;
  const __bf16* kg = ksrc + 2 * kstep;
  const __bf16* vg = vsrc + 64;

  for (int tp = 0; tp < 15; ++tp) {
    attn_iter<16384, 8192, 0, 24576, true>(st, kg, vg, qf, sA, sB, o0, o1, rs);
    kg += kstep; vg += 64;
    attn_iter<0, 24576, 16384, 8192, true>(st, kg, vg, qf, sB, sA, o0, o1, rs);
    kg += kstep; vg += 64;
  }
  attn_iter<16384, 8192, 0, 24576, false>(st, kg, vg, qf, sA, sB, o0, o1, rs);

  {
    __syncthreads();
    bf16x8 vf[2][4];
#pragma unroll
    for (int db = 0; db < 2; db++)
#pragma unroll
      for (int k2 = 0; k2 < 4; k2++)
        vf[db][k2] = *(const bf16x8*)(st.lbase + st.lb[db][k2] + 24576);
    bf16x8 ap[4];
#pragma unroll
    for (int kb = 0; kb < 2; kb++) {
      float pv[16];
#pragma unroll
      for (int r = 0; r < 16; r++) {
        pv[r] = __builtin_amdgcn_exp2f(sB[kb][r]);
        rs += pv[r];
      }
#pragma unroll
      for (int hf = 0; hf < 2; hf++) {
        unsigned w0 = cvt_pk_bf16(pv[hf * 8 + 0], pv[hf * 8 + 1]);
        unsigned w1 = cvt_pk_bf16(pv[hf * 8 + 2], pv[hf * 8 + 3]);
        unsigned w2 = cvt_pk_bf16(pv[hf * 8 + 4], pv[hf * 8 + 5]);
        unsigned w3 = cvt_pk_bf16(pv[hf * 8 + 6], pv[hf * 8 + 7]);
        permswap(w0, w2);
        permswap(w1, w3);
        union { unsigned u[4]; bf16x8 v; } pk;
        pk.u[0] = w0; pk.u[1] = w1; pk.u[2] = w2; pk.u[3] = w3;
        ap[kb * 2 + hf] = pk.v;
      }
    }
#pragma unroll
    for (int k2 = 0; k2 < 4; k2++) {
      o0 = MFMA32(ap[k2], vf[0][k2], o0);
      o1 = MFMA32(ap[k2], vf[1][k2], o1);
    }
  }

  unsigned xu = __float_as_uint(rs), yu = __float_as_uint(rs);
  permswap(xu, yu);
  float inv = 1.0f / (__uint_as_float(xu) + __uint_as_float(yu));
  float invv[16];
#pragma unroll
  for (int r = 0; r < 16; r++)
    invv[r] = __shfl(inv, (r & 3) + 8 * (r >> 2) + 4 * hi);

  __bf16* ob = O + (size_t)(b * T + q0 + wave * 32) * 1024 + h * 64 + l32;
#pragma unroll
  for (int r = 0; r < 16; r++) {
    int row = (r & 3) + 8 * (r >> 2) + 4 * hi;
    ob[(size_t)row * 1024] = (__bf16)(o0[r] * invv[r]);
    ob[(size_t)row * 1024 + 32] = (__bf16)(o1[r] * invv[r]);
  }
}

// ---------------- launch ----------------
extern "C" void kernel_launch(void* const* d_in, const int* in_sizes, int n_in,
                              void* d_out, int out_size, void* d_ws, size_t ws_size,
                              hipStream_t stream) {
  const float* x = (const float*)d_in[0];      // [2,2048,1024]
  const float* W_qkv = (const float*)d_in[1];  // [1024,3072]
  const float* b_qkv = (const float*)d_in[2];  // [3072]
  const float* W_out = (const float*)d_in[3];  // [1024,1024]
  const float* b_out = (const float*)d_in[4];  // [1024]
  float* out = (float*)d_out;                  // [2,2048,1024] f32

  char* ws = (char*)d_ws;
  __bf16* WqkvT = (__bf16*)(ws);               // [3072][1024]  6 MB
  __bf16* WoT = (__bf16*)(ws + 6291456);       // [1024][1024]  2 MB
  __bf16* xb = (__bf16*)(ws + 8388608);        // [4096][1024]  8 MB
  __bf16* qkvb = (__bf16*)(ws + 16777216);     // [4096][3072] 24 MB
  __bf16* Vt = (__bf16*)(ws + 41943040);       // [2][16][64][2048] 8 MB
  __bf16* attnb = xb;  // xb dead after gemm1; reuse for attention output

  const float cs = 0.125f * 1.44269504089f;  // 1/sqrt(64) * log2(e)

  prep_kernel<<<8192, 256, 0, stream>>>(x, xb, W_qkv, WqkvT, W_out, WoT);
  gemm_kernel<false, 128><<<dim3(32, 24), 256, 0, stream>>>(xb, WqkvT, b_qkv, qkvb, 3072,
                                                            1024, cs, Vt);
  attn_kernel<<<dim3(8, 64), 256, 0, stream>>>(qkvb, Vt, attnb);
  gemm_kernel<true, 64><<<dim3(32, 16), 256, 0, stream>>>(attnb, WoT, b_out, out, 1024,
                                                          0, 1.0f, nullptr);
}

// Round 9
// 176.543 us; speedup vs baseline: 1.1211x; 1.1211x over previous
//
#include <hip/hip_runtime.h>

typedef __bf16 bf16x8 __attribute__((ext_vector_type(8)));
typedef float f32x4 __attribute__((ext_vector_type(4)));
typedef float f32x16 __attribute__((ext_vector_type(16)));

#define MFMA16(a, b, c) __builtin_amdgcn_mfma_f32_16x16x32_bf16(a, b, c, 0, 0, 0)
#define MFMA32(a, b, c) __builtin_amdgcn_mfma_f32_32x32x16_bf16(a, b, c, 0, 0, 0)
#define GLDS16(g, l)                                                              \
  __builtin_amdgcn_global_load_lds((const __attribute__((address_space(1))) void*)(g), \
                                   (__attribute__((address_space(3))) void*)(l), 16, 0, 0)

static __device__ __forceinline__ unsigned cvt_pk_bf16(float lo, float hi) {
  unsigned r;
  asm("v_cvt_pk_bf16_f32 %0, %1, %2" : "=v"(r) : "v"(lo), "v"(hi));
  return r;
}
// v_permlane32_swap_b32: a'[l<32]=a[l], a'[l>=32]=b[l-32], b'[l<32]=a[l+32], b'[l>=32]=b[l]
static __device__ __forceinline__ void permswap(unsigned& a, unsigned& b) {
  asm("v_permlane32_swap_b32 %0, %1" : "+v"(a), "+v"(b));
}

// ---------------- prep: cvt x->bf16 (blocks 0-4095) + transpose both weights ----------------
__global__ __launch_bounds__(256) void prep_kernel(const float* __restrict__ x,
                                                   __bf16* __restrict__ xb,
                                                   const float* __restrict__ Wq,
                                                   __bf16* __restrict__ WqT,
                                                   const float* __restrict__ Wo,
                                                   __bf16* __restrict__ WoT) {
  __shared__ float tile[32][33];
  int bid = blockIdx.x;
  int tid = threadIdx.x;
  if (bid < 4096) {  // cvt: 1048576 float4 chunks
    int i = bid * 256 + tid;
    float4 v = ((const float4*)x)[i];
    union { __bf16 b[4]; uint2 u; } t;
    t.b[0] = (__bf16)v.x; t.b[1] = (__bf16)v.y;
    t.b[2] = (__bf16)v.z; t.b[3] = (__bf16)v.w;
    ((uint2*)xb)[i] = t.u;
    return;
  }
  // transpose-convert weights (block-uniform path; barrier only inside this branch)
  const int Kd = 1024;
  int b2 = bid - 4096;
  int bx = b2 & 127;
  int k0 = (b2 >> 7) * 32;
  const float* W; __bf16* WT; int Nd, n0;
  if (bx < 96) { W = Wq; WT = WqT; Nd = 3072; n0 = bx * 32; }
  else         { W = Wo; WT = WoT; Nd = 1024; n0 = (bx - 96) * 32; }
  int kk = tid >> 3, nn = (tid & 7) * 4;
  float4 v = *(const float4*)&W[(size_t)(k0 + kk) * Nd + n0 + nn];
  tile[kk][nn] = v.x; tile[kk][nn + 1] = v.y;
  tile[kk][nn + 2] = v.z; tile[kk][nn + 3] = v.w;
  __syncthreads();
  int n2 = tid >> 3, k2 = (tid & 7) * 4;
  union { __bf16 b[4]; uint2 u; } t;
  t.b[0] = (__bf16)tile[k2][n2];
  t.b[1] = (__bf16)tile[k2 + 1][n2];
  t.b[2] = (__bf16)tile[k2 + 2][n2];
  t.b[3] = (__bf16)tile[k2 + 3][n2];
  *(uint2*)&WT[(size_t)(n0 + n2) * Kd + k0 + k2] = t.u;
}

// ---------------- GEMM: C[M,N] = A[M,1024] @ BT[N,1024]^T + bias ----------------
// Round-4 verified core. XCD 2D-chunk swizzle (T1): 1D grid; hardware assigns
// consecutive wg ids round-robin to the 8 XCDs, so id&7 ~ XCD. Each XCD owns an
// 8(M) x CBY(N) chunk of tiles: A-panels 2MB + B-panels <=3MB ~ L2-resident
// (vs default round-robin where each XCD touches all 14MB of A+B -> 2x over-fetch,
// FETCH_SIZE 28.8MB measured). Bijective: grid = 32*(4/... ) divisible by 8.
template <bool OUT_F32, int NT, int CBY>
__global__ __launch_bounds__(256) void gemm_kernel(const __bf16* __restrict__ A,
                                                   const __bf16* __restrict__ BT,
                                                   const float* __restrict__ bias,
                                                   void* __restrict__ Cout, int N,
                                                   int qn, float qs) {
  const int K = 1024;
  const int NJ = NT / 32;
  __shared__ __align__(16) __bf16 As[128 * 32];
  __shared__ __align__(16) __bf16 Bs[NT * 32];
  int tid = threadIdx.x;
  int wave = tid >> 6, lane = tid & 63;
  int quad = lane >> 4, l16 = lane & 15;
  int id = blockIdx.x;
  int xcd = id & 7, r = id >> 3;
  int m0 = ((xcd & 3) * 8 + (r & 7)) * 128;        // 32 M-tiles = 4 chunks of 8
  int n0 = ((xcd >> 2) * CBY + (r >> 3)) * NT;     // N-tiles = 2 chunks of CBY
  int wm = (wave >> 1) * 64, wn = (wave & 1) * (NT / 2);

  int srow = tid >> 2, scol = (tid & 3) * 8;
  const __bf16* aptr = A + (size_t)(m0 + srow) * K + scol;
  const __bf16* bptr = BT + (size_t)(n0 + srow) * K + scol;
  __bf16* asl = &As[(size_t)wave * 512];
  __bf16* bsl = &Bs[(size_t)wave * 512];

  f32x4 acc[4][NJ] = {};
  for (int k0 = 0; k0 < K; k0 += 32) {
    GLDS16(aptr + k0, asl);
    GLDS16(aptr + (size_t)64 * K + k0, asl + 2048);
    GLDS16(bptr + k0, bsl);
    if (NT == 128) GLDS16(bptr + (size_t)64 * K + k0, bsl + 2048);
    __syncthreads();
    bf16x8 af[4], bf[NJ];
    for (int i = 0; i < 4; i++)
      af[i] = *(bf16x8*)&As[(wm + i * 16 + l16) * 32 + quad * 8];
    for (int j = 0; j < NJ; j++)
      bf[j] = *(bf16x8*)&Bs[(wn + j * 16 + l16) * 32 + quad * 8];
    for (int i = 0; i < 4; i++)
      for (int j = 0; j < NJ; j++)
        acc[i][j] = MFMA16(af[i], bf[j], acc[i][j]);
    __syncthreads();
  }
  for (int j = 0; j < NJ; j++) {
    int col = n0 + wn + j * 16 + l16;
    float bv = bias[col];
    float sc = (col < qn) ? qs : 1.0f;
    for (int i = 0; i < 4; i++) {
      int rowb = m0 + wm + i * 16 + quad * 4;
      for (int r2 = 0; r2 < 4; r2++) {
        float v = (acc[i][j][r2] + bv) * sc;
        if (OUT_F32)
          ((float*)Cout)[(size_t)(rowb + r2) * N + col] = v;
        else
          ((__bf16*)Cout)[(size_t)(rowb + r2) * N + col] = (__bf16)v;
      }
    }
  }
}

// ---------------- transpose V slice of qkv -> Vt [b][h][d][t] ----------------
__global__ __launch_bounds__(256) void transpose_v_kernel(const __bf16* __restrict__ qkv,
                                                          __bf16* __restrict__ Vt) {
  const int T = 2048, C3 = 3072;
  __shared__ __align__(16) __bf16 tile[64][72];
  int t0 = blockIdx.x * 64;
  int h = blockIdx.y, b = blockIdx.z;
  int tid = threadIdx.x;
  int tt = tid >> 2, c = (tid & 3) * 16;
  const __bf16* src = qkv + (size_t)(b * T + t0 + tt) * C3 + 2048 + h * 64 + c;
  *(uint4*)&tile[tt][c] = *(const uint4*)src;
  *(uint4*)&tile[tt][c + 8] = *(const uint4*)(src + 8);
  __syncthreads();
  int dd = tid >> 2, t2 = (tid & 3) * 16;
  union { __bf16 b_[16]; uint4 u[2]; } o;
  for (int i = 0; i < 16; i++) o.b_[i] = tile[t2 + i][dd];
  __bf16* dst = Vt + ((size_t)(b * 16 + h) * 64 + dd) * T + t0 + t2;
  *(uint4*)dst = o.u[0];
  *(uint4*)(dst + 8) = o.u[1];
}

// ---------------- flash attention: T15 pipeline + 2nd-order XOR swizzle ----------------
// Swapped QK^T (S^T = mfma(K,Q)); in-register softmax via cvt_pk+permlane32_swap.
// Pipeline: iter t runs QK(t+1) [MFMA] then softmax(t) [VALU] then PV(t) [MFMA].
// LDS: single arena KV[4] = {K0,V0,K1,V1}, compile-time buffer selection.
// Swizzle slot = logical ^ (row&7) ^ ((row>>3)&7), applied on both sides.
struct AttnState {
  const char* lbase;
  char* wdst;
  int dK, dV;     // element deltas: +32 rows incl. swizzle adjustment
  int lb[2][4];
};

template <int KRD, int VRD, int KST, int VST, bool DO_KST>
__device__ __forceinline__ void attn_iter(const AttnState& st, const __bf16* kg,
                                          const __bf16* vg, const bf16x8 (&qf)[4],
                                          const f32x16* sIN, f32x16* sOUT, f32x16& o0,
                                          f32x16& o1, float& rs) {
  __syncthreads();  // drains own vmcnt: K(t+1),V(t) landed (all waves) before reads
  if constexpr (DO_KST) {
    GLDS16(kg, st.wdst + KST);
    GLDS16(kg + st.dK, st.wdst + KST + 4096);
  }
  GLDS16(vg, st.wdst + VST);
  GLDS16(vg + st.dV, st.wdst + VST + 4096);

  bf16x8 kf[2][4], vf[2][4];
#pragma unroll
  for (int rb = 0; rb < 2; rb++)
#pragma unroll
    for (int ds = 0; ds < 4; ds++)
      kf[rb][ds] = *(const bf16x8*)(st.lbase + st.lb[rb][ds] + KRD);
#pragma unroll
  for (int db = 0; db < 2; db++)
#pragma unroll
    for (int k2 = 0; k2 < 4; k2++)
      vf[db][k2] = *(const bf16x8*)(st.lbase + st.lb[db][k2] + VRD);

  f32x16 s0 = {}, s1 = {};
#pragma unroll
  for (int ds = 0; ds < 4; ds++) {
    s0 = MFMA32(kf[0][ds], qf[ds], s0);
    s1 = MFMA32(kf[1][ds], qf[ds], s1);
  }
  sOUT[0] = s0;
  sOUT[1] = s1;

  bf16x8 ap[4];
#pragma unroll
  for (int kb = 0; kb < 2; kb++) {
    float pv[16];
#pragma unroll
    for (int r = 0; r < 16; r++) {
      pv[r] = __builtin_amdgcn_exp2f(sIN[kb][r]);
      rs += pv[r];
    }
#pragma unroll
    for (int hf = 0; hf < 2; hf++) {
      unsigned w0 = cvt_pk_bf16(pv[hf * 8 + 0], pv[hf * 8 + 1]);
      unsigned w1 = cvt_pk_bf16(pv[hf * 8 + 2], pv[hf * 8 + 3]);
      unsigned w2 = cvt_pk_bf16(pv[hf * 8 + 4], pv[hf * 8 + 5]);
      unsigned w3 = cvt_pk_bf16(pv[hf * 8 + 6], pv[hf * 8 + 7]);
      permswap(w0, w2);
      permswap(w1, w3);
      union { unsigned u[4]; bf16x8 v; } pk;
      pk.u[0] = w0; pk.u[1] = w1; pk.u[2] = w2; pk.u[3] = w3;
      ap[kb * 2 + hf] = pk.v;
    }
  }

#pragma unroll
  for (int k2 = 0; k2 < 4; k2++) {
    o0 = MFMA32(ap[k2], vf[0][k2], o0);
    o1 = MFMA32(ap[k2], vf[1][k2], o1);
  }
}

__global__ __launch_bounds__(256, 2) void attn_kernel(const __bf16* __restrict__ qkv,
                                                      const __bf16* __restrict__ Vt,
                                                      __bf16* __restrict__ O) {
  const int T = 2048, C3 = 3072;
  int p = blockIdx.x * 4 + (blockIdx.y >> 4);
  int b = p >> 4, h = p & 15;
  int q0 = (blockIdx.y & 15) * 128;

  int tid = threadIdx.x, wave = tid >> 6, lane = tid & 63;
  int l32 = lane & 31, hi = lane >> 5;

  __shared__ __align__(16) __bf16 KV[4][64 * 64];

  const __bf16* qp = qkv + (size_t)(b * T + q0 + wave * 32 + l32) * C3 + h * 64;
  bf16x8 qf[4];
#pragma unroll
  for (int ds = 0; ds < 4; ds++)
    qf[ds] = *(const bf16x8*)(qp + ds * 16 + hi * 8);

  const __bf16* kbase = qkv + (size_t)(b * T) * C3 + 1024 + h * 64;
  const __bf16* vbase = Vt + (size_t)(b * 16 + h) * 64 * T;

  int srow = wave * 8 + (lane >> 3);
  int sx1 = ((lane & 7) ^ (lane >> 3) ^ wave) * 8;
  int sx2 = sx1 ^ 32;  // (^4 col-blocks) * 8 elem
  const __bf16* ksrc = kbase + (size_t)srow * C3 + sx1;
  const __bf16* vsrc = vbase + (size_t)srow * T + sx1;

  AttnState st;
  st.lbase = (const char*)&KV[0][0];
  st.wdst = (char*)&KV[0][0] + wave * 1024;
  st.dK = 32 * C3 + (sx2 - sx1);
  st.dV = 32 * T + (sx2 - sx1);
#pragma unroll
  for (int rb = 0; rb < 2; rb++)
#pragma unroll
    for (int c4 = 0; c4 < 4; c4++)
      st.lb[rb][c4] =
          ((rb * 32 + l32) * 64 +
           (((c4 * 2 + hi) ^ (l32 & 7) ^ (l32 >> 3) ^ (rb * 4)) * 8)) * 2;

  f32x16 o0 = {}, o1 = {};
  f32x16 sA[2], sB[2];
  float rs = 0.0f;

  GLDS16(ksrc, st.wdst + 0);
  GLDS16(ksrc + st.dK, st.wdst + 4096);
  GLDS16(vsrc, st.wdst + 8192);
  GLDS16(vsrc + st.dV, st.wdst + 8192 + 4096);
  GLDS16(ksrc + (size_t)64 * C3, st.wdst + 16384);
  GLDS16(ksrc + (size_t)64 * C3 + st.dK, st.wdst + 16384 + 4096);
  __syncthreads();

  {
    bf16x8 kf[2][4];
#pragma unroll
    for (int rb = 0; rb < 2; rb++)
#pragma unroll
      for (int ds = 0; ds < 4; ds++)
        kf[rb][ds] = *(const bf16x8*)(st.lbase + st.lb[rb][ds] + 0);
    f32x16 s0 = {}, s1 = {};
#pragma unroll
    for (int ds = 0; ds < 4; ds++) {
      s0 = MFMA32(kf[0][ds], qf[ds], s0);
      s1 = MFMA32(kf[1][ds], qf[ds], s1);
    }
    sA[0] = s0;
    sA[1] = s1;
  }

  const size_t kstep = (size_t)64 * C3;
  const __bf16* kg = ksrc + 2 * kstep;
  const __bf16* vg = vsrc + 64;

  for (int tp = 0; tp < 15; ++tp) {
    attn_iter<16384, 8192, 0, 24576, true>(st, kg, vg, qf, sA, sB, o0, o1, rs);
    kg += kstep; vg += 64;
    attn_iter<0, 24576, 16384, 8192, true>(st, kg, vg, qf, sB, sA, o0, o1, rs);
    kg += kstep; vg += 64;
  }
  attn_iter<16384, 8192, 0, 24576, false>(st, kg, vg, qf, sA, sB, o0, o1, rs);

  {
    __syncthreads();
    bf16x8 vf[2][4];
#pragma unroll
    for (int db = 0; db < 2; db++)
#pragma unroll
      for (int k2 = 0; k2 < 4; k2++)
        vf[db][k2] = *(const bf16x8*)(st.lbase + st.lb[db][k2] + 24576);
    bf16x8 ap[4];
#pragma unroll
    for (int kb = 0; kb < 2; kb++) {
      float pv[16];
#pragma unroll
      for (int r = 0; r < 16; r++) {
        pv[r] = __builtin_amdgcn_exp2f(sB[kb][r]);
        rs += pv[r];
      }
#pragma unroll
      for (int hf = 0; hf < 2; hf++) {
        unsigned w0 = cvt_pk_bf16(pv[hf * 8 + 0], pv[hf * 8 + 1]);
        unsigned w1 = cvt_pk_bf16(pv[hf * 8 + 2], pv[hf * 8 + 3]);
        unsigned w2 = cvt_pk_bf16(pv[hf * 8 + 4], pv[hf * 8 + 5]);
        unsigned w3 = cvt_pk_bf16(pv[hf * 8 + 6], pv[hf * 8 + 7]);
        permswap(w0, w2);
        permswap(w1, w3);
        union { unsigned u[4]; bf16x8 v; } pk;
        pk.u[0] = w0; pk.u[1] = w1; pk.u[2] = w2; pk.u[3] = w3;
        ap[kb * 2 + hf] = pk.v;
      }
    }
#pragma unroll
    for (int k2 = 0; k2 < 4; k2++) {
      o0 = MFMA32(ap[k2], vf[0][k2], o0);
      o1 = MFMA32(ap[k2], vf[1][k2], o1);
    }
  }

  unsigned xu = __float_as_uint(rs), yu = __float_as_uint(rs);
  permswap(xu, yu);
  float inv = 1.0f / (__uint_as_float(xu) + __uint_as_float(yu));
  float invv[16];
#pragma unroll
  for (int r = 0; r < 16; r++)
    invv[r] = __shfl(inv, (r & 3) + 8 * (r >> 2) + 4 * hi);

  __bf16* ob = O + (size_t)(b * T + q0 + wave * 32) * 1024 + h * 64 + l32;
#pragma unroll
  for (int r = 0; r < 16; r++) {
    int row = (r & 3) + 8 * (r >> 2) + 4 * hi;
    ob[(size_t)row * 1024] = (__bf16)(o0[r] * invv[r]);
    ob[(size_t)row * 1024 + 32] = (__bf16)(o1[r] * invv[r]);
  }
}

// ---------------- launch ----------------
extern "C" void kernel_launch(void* const* d_in, const int* in_sizes, int n_in,
                              void* d_out, int out_size, void* d_ws, size_t ws_size,
                              hipStream_t stream) {
  const float* x = (const float*)d_in[0];      // [2,2048,1024]
  const float* W_qkv = (const float*)d_in[1];  // [1024,3072]
  const float* b_qkv = (const float*)d_in[2];  // [3072]
  const float* W_out = (const float*)d_in[3];  // [1024,1024]
  const float* b_out = (const float*)d_in[4];  // [1024]
  float* out = (float*)d_out;                  // [2,2048,1024] f32

  char* ws = (char*)d_ws;
  __bf16* WqkvT = (__bf16*)(ws);               // [3072][1024]  6 MB
  __bf16* WoT = (__bf16*)(ws + 6291456);       // [1024][1024]  2 MB
  __bf16* xb = (__bf16*)(ws + 8388608);        // [4096][1024]  8 MB
  __bf16* qkvb = (__bf16*)(ws + 16777216);     // [4096][3072] 24 MB
  __bf16* Vt = (__bf16*)(ws + 41943040);       // [2][16][64][2048] 8 MB
  __bf16* attnb = xb;  // xb dead after gemm1; reuse for attention output

  const float cs = 0.125f * 1.44269504089f;  // 1/sqrt(64) * log2(e)

  prep_kernel<<<8192, 256, 0, stream>>>(x, xb, W_qkv, WqkvT, W_out, WoT);
  gemm_kernel<false, 128, 12><<<768, 256, 0, stream>>>(xb, WqkvT, b_qkv, qkvb, 3072,
                                                       1024, cs);
  transpose_v_kernel<<<dim3(32, 16, 2), 256, 0, stream>>>(qkvb, Vt);
  attn_kernel<<<dim3(8, 64), 256, 0, stream>>>(qkvb, Vt, attnb);
  gemm_kernel<true, 64, 8><<<512, 256, 0, stream>>>(attnb, WoT, b_out, out, 1024,
                                                    0, 1.0f);
}